// Round 7
// baseline (757.715 us; speedup 1.0000x reference)
//
#include <hip/hip_runtime.h>
#include <hip/hip_bf16.h>

// LightGCN forward on MI355X — round 7.
// r6 evidence: counting-sort scatter's coalesced write-out works (WRITE 181->88MB)
//   but 111KB LDS -> 1 block/CU (occ 9.6%), 3.3M bank conflicts -> 273us.
// r7: stage a ushort PERMUTATION (16KB) instead of data+dst (96KB); write-out
//   re-reads edges via perm (L2-hot window) and derives dst arithmetically.
//   LDS ~31KB -> 5 blocks/CU.

#define N_USERS  100000
#define N_ITEMS  50000
#define N_TOTAL  150000          // N_USERS + N_ITEMS
#define D        64
#define NNZ      6400000
#define BATCH    4096
#define NELEM    (N_TOTAL * D)   // 9,600,000
#define RPB      128                          // rows per bucket (row >> 7)
#define NBUK     ((N_TOTAL + RPB - 1) / RPB)  // 1172
#define CAP      8192            // per-bucket pair capacity (mean 5461, sigma 74)
#define CHUNK    8192
#define EB       ((NNZ + CHUNK - 1) / CHUNK)  // 782
#define SORTCAP  8192
#define BPT      ((NBUK + 255) / 256)         // buckets per thread in block scan = 5

__device__ __forceinline__ float bf2f(unsigned short h) {
    return __uint_as_float(((unsigned int)h) << 16);
}

// ---------- init: A = bf16(concat(user,item)); zero bucket cursors ----------
__global__ void lgcn_init(const float* __restrict__ user_emb,
                          const float* __restrict__ item_emb,
                          unsigned short* __restrict__ A,
                          int* __restrict__ cursor) {
    int i = blockIdx.x * blockDim.x + threadIdx.x;
    if (i < NELEM) {
        float v = (i < N_USERS * D) ? user_emb[i] : item_emb[i - N_USERS * D];
        __hip_bfloat16 b = __float2bfloat16(v);   // RNE
        A[i] = *(unsigned short*)&b;
    }
    if (i < NBUK) cursor[i] = 0;
}

// ---------- scatter: LDS permutation counting sort, coalesced write-out ----------
// pair.x = (local_row<<18) | col   (col < 2^18, local_row < 128)
__global__ void __launch_bounds__(256)
lgcn_bucket_scatter(const int*   __restrict__ rows,
                    const int*   __restrict__ cols,
                    const float* __restrict__ vals,
                    int*         __restrict__ cursor,
                    int2*        __restrict__ pairs) {
    __shared__ unsigned short perm[CHUNK];  // 16 KB: sorted pos -> local edge idx
    __shared__ int lhist[NBUK];             // 4.7 KB (counts, then local cursor)
    __shared__ int lbase_l[NBUK];           // 4.7 KB (local sorted base)
    __shared__ int lbase_g[NBUK];           // 4.7 KB (global reservation offset)
    __shared__ int tscan[256];              // 1 KB        => ~31 KB, 5 blocks/CU

    int tid = threadIdx.x;
    int s = blockIdx.x * CHUNK;
    int e_end = s + CHUNK; if (e_end > NNZ) e_end = NNZ;
    int n = e_end - s;

    for (int i = tid; i < NBUK; i += 256) lhist[i] = 0;
    __syncthreads();
    for (int e = s + tid; e < e_end; e += 256)
        atomicAdd(&lhist[rows[e] >> 7], 1);
    __syncthreads();

    // block-wide exclusive scan of lhist: BPT buckets/thread + 256-wide LDS scan
    int my[BPT];
    int tsum = 0;
    #pragma unroll
    for (int k = 0; k < BPT; k++) {
        int idx = tid * BPT + k;
        int c = (idx < NBUK) ? lhist[idx] : 0;
        my[k] = tsum;
        tsum += c;
    }
    tscan[tid] = tsum;
    __syncthreads();
    for (int off = 1; off < 256; off <<= 1) {
        int u = (tid >= off) ? tscan[tid - off] : 0;
        __syncthreads();
        tscan[tid] += u;
        __syncthreads();
    }
    int texcl = tscan[tid] - tsum;
    #pragma unroll
    for (int k = 0; k < BPT; k++) {
        int idx = tid * BPT + k;
        if (idx < NBUK) {
            int c = lhist[idx];
            lbase_l[idx] = texcl + my[k];
            lbase_g[idx] = c ? atomicAdd(&cursor[idx], c) : 0;
        }
    }
    __syncthreads();
    for (int i = tid; i < NBUK; i += 256) lhist[i] = 0;   // reuse as local cursor
    __syncthreads();

    // pass 2: rank edges, record permutation (2B LDS stores)
    for (int e = s + tid; e < e_end; e += 256) {
        int bk = rows[e] >> 7;
        int rank = atomicAdd(&lhist[bk], 1);
        perm[lbase_l[bk] + rank] = (unsigned short)(e - s);
    }
    __syncthreads();

    // pass 3: write out in sorted order; dst derived arithmetically.
    // rows/cols/vals re-reads hit L1/L2 (chunk window is 96 KB, just touched).
    for (int i = tid; i < n; i += 256) {
        int e = s + (int)perm[i];
        int r = rows[e];
        int bk = r >> 7;
        int o = lbase_g[bk] + (i - lbase_l[bk]);
        int2 p;
        p.x = ((r & 127) << 18) | cols[e];
        p.y = __float_as_int(vals[e]);
        pairs[(o < CAP) ? ((size_t)bk * CAP + o) : ((size_t)NBUK * CAP)] = p;
    }
}

// ---------- in-LDS exact sort within each bucket; emit row_ptr/row_cnt ----------
__global__ void __launch_bounds__(256)
lgcn_bucket_sort(int2* __restrict__ pairs,
                 const int* __restrict__ cursor,
                 int* __restrict__ row_ptr,
                 int* __restrict__ row_cnt) {
    __shared__ int2 buf[SORTCAP];      // 64 KB
    __shared__ int  h[RPB];
    __shared__ int  base[RPB];
    int tid = threadIdx.x;
    int b = blockIdx.x;
    int start = b * CAP;
    int cnt   = cursor[b];
    if (cnt > SORTCAP) cnt = SORTCAP;  // unreachable for this data; safety only

    for (int i = tid; i < cnt; i += 256) buf[i] = pairs[start + i];
    for (int i = tid; i < RPB; i += 256) h[i] = 0;
    __syncthreads();
    for (int i = tid; i < cnt; i += 256) atomicAdd(&h[buf[i].x >> 18], 1);
    __syncthreads();

    // exclusive scan of h[0..127]
    int v = (tid < RPB) ? h[tid] : 0;
    int sum = v;
    #pragma unroll
    for (int off = 1; off < RPB; off <<= 1) {
        if (tid < RPB) base[tid] = sum;
        __syncthreads();
        if (tid >= off && tid < RPB) sum += base[tid - off];
        __syncthreads();
    }
    if (tid < RPB) {
        int excl = sum - v;
        base[tid] = excl;
        int gr = b * RPB + tid;
        if (gr < N_TOTAL) {
            row_ptr[gr] = start + excl;
            row_cnt[gr] = v;
        }
        h[tid] = 0;                    // reuse as per-row cursor
    }
    __syncthreads();

    for (int i = tid; i < cnt; i += 256) {
        int2 p = buf[i];
        int lr = p.x >> 18;
        int rank = atomicAdd(&h[lr], 1);
        pairs[start + base[lr] + rank] = p;   // random within 64KB window -> L2
    }
}

// ---------- SpMM: wave per row, bf16 gathers, bf16 output ----------
__global__ void lgcn_spmm_csr(const int2* __restrict__ pairs,
                              const int*  __restrict__ row_ptr,
                              const int*  __restrict__ row_cnt,
                              const unsigned short* __restrict__ cur,
                              unsigned short* __restrict__ nxt) {
    int t = blockIdx.x * blockDim.x + threadIdx.x;
    int r = t >> 6;
    int lane = t & 63;
    if (r >= N_TOTAL) return;
    int start = row_ptr[r];
    int cnt   = row_cnt[r];
    float sum0 = 0.f, sum1 = 0.f;
    for (int base = 0; base < cnt; base += 64) {
        int idx = base + lane;
        int2 p = {0, 0};
        if (idx < cnt) p = pairs[start + idx];     // coalesced dwordx2
        int m = cnt - base; if (m > 64) m = 64;
        int j = 0;
        for (; j + 8 <= m; j += 8) {               // 8 outstanding gathers
            float acc[8];
            #pragma unroll
            for (int k = 0; k < 8; k++) {
                int   c = __shfl(p.x, j + k, 64);
                float v = __int_as_float(__shfl(p.y, j + k, 64));
                acc[k] = v * bf2f(cur[(c & 0x3FFFF) * D + lane]);
            }
            sum0 += acc[0] + acc[2] + acc[4] + acc[6];
            sum1 += acc[1] + acc[3] + acc[5] + acc[7];
        }
        for (; j < m; j++) {
            int   c = __shfl(p.x, j, 64);
            float v = __int_as_float(__shfl(p.y, j, 64));
            sum0 += v * bf2f(cur[(c & 0x3FFFF) * D + lane]);
        }
    }
    __hip_bfloat16 o = __float2bfloat16(sum0 + sum1);   // RNE
    nxt[r * D + lane] = *(unsigned short*)&o;
}

// ---------- layer 3 at sampled rows only: e3[s,:] = (A @ E2)[row(s),:] (f32) ----
__global__ void lgcn_spmm_sampled(const int2* __restrict__ pairs,
                                  const int*  __restrict__ row_ptr,
                                  const int*  __restrict__ row_cnt,
                                  const unsigned short* __restrict__ cur,
                                  const int* __restrict__ users,
                                  const int* __restrict__ items,
                                  float* __restrict__ e3) {
    int t = blockIdx.x * blockDim.x + threadIdx.x;
    int s = t >> 6;
    int lane = t & 63;
    if (s >= 2 * BATCH) return;
    int r = (s < BATCH) ? users[s] : (N_USERS + items[s - BATCH]);
    int start = row_ptr[r];
    int cnt   = row_cnt[r];
    float sum0 = 0.f, sum1 = 0.f;
    for (int base = 0; base < cnt; base += 64) {
        int idx = base + lane;
        int2 p = {0, 0};
        if (idx < cnt) p = pairs[start + idx];
        int m = cnt - base; if (m > 64) m = 64;
        int j = 0;
        for (; j + 8 <= m; j += 8) {
            float acc[8];
            #pragma unroll
            for (int k = 0; k < 8; k++) {
                int   c = __shfl(p.x, j + k, 64);
                float v = __int_as_float(__shfl(p.y, j + k, 64));
                acc[k] = v * bf2f(cur[(c & 0x3FFFF) * D + lane]);
            }
            sum0 += acc[0] + acc[2] + acc[4] + acc[6];
            sum1 += acc[1] + acc[3] + acc[5] + acc[7];
        }
        for (; j < m; j++) {
            int   c = __shfl(p.x, j, 64);
            float v = __int_as_float(__shfl(p.y, j, 64));
            sum0 += v * bf2f(cur[(c & 0x3FFFF) * D + lane]);
        }
    }
    e3[s * D + lane] = sum0 + sum1;
}

// ---------- dot: gamma = <E0+E1+E2+E3>_u . <E0+E1+E2+E3>_i / 16 ----------
__global__ void lgcn_dot(const float* __restrict__ user_emb,
                         const float* __restrict__ item_emb,
                         const unsigned short* __restrict__ E1,
                         const unsigned short* __restrict__ E2,
                         const float* __restrict__ e3,
                         const int* __restrict__ users,
                         const int* __restrict__ items,
                         float* __restrict__ out) {
    int t = blockIdx.x * blockDim.x + threadIdx.x;
    int b = t >> 6;
    int d = t & 63;
    if (b < BATCH) {
        int u  = users[b];
        int it = items[b];
        int ur = u * D + d;
        int ir = (N_USERS + it) * D + d;
        float au = user_emb[ur] + bf2f(E1[ur]) + bf2f(E2[ur]) + e3[b * D + d];
        float ai = item_emb[it * D + d] + bf2f(E1[ir]) + bf2f(E2[ir])
                 + e3[(BATCH + b) * D + d];
        float p = au * ai;
        #pragma unroll
        for (int off = 32; off; off >>= 1) p += __shfl_down(p, off, 64);
        if (d == 0) out[b] = p * (1.0f / 16.0f);
    }
}

// ---------- round-1 fallback (atomic scatter) if ws too small ----------
__global__ void lgcn_init_fb(const float* __restrict__ user_emb,
                             const float* __restrict__ item_emb,
                             float* __restrict__ acc,
                             float* __restrict__ cur,
                             float* __restrict__ nxt) {
    int i = blockIdx.x * blockDim.x + threadIdx.x;
    if (i < NELEM) {
        float v = (i < N_USERS * D) ? user_emb[i] : item_emb[i - N_USERS * D];
        acc[i] = v; cur[i] = v; nxt[i] = 0.0f;
    }
}
__global__ void lgcn_spmm_fb(const int* __restrict__ rows,
                             const int* __restrict__ cols,
                             const float* __restrict__ vals,
                             const float* __restrict__ cur,
                             float* __restrict__ nxt) {
    long long t = (long long)blockIdx.x * blockDim.x + threadIdx.x;
    int e = (int)(t >> 6);
    int d = (int)(t & 63);
    if (e < NNZ) {
        float x = cur[cols[e] * D + d];
        unsafeAtomicAdd(&nxt[rows[e] * D + d], vals[e] * x);
    }
}
__global__ void lgcn_accum_fb(float* __restrict__ acc,
                              const float* __restrict__ src,
                              float* __restrict__ to_zero) {
    int i = blockIdx.x * blockDim.x + threadIdx.x;
    if (i < NELEM) {
        acc[i] += src[i];
        if (to_zero) to_zero[i] = 0.0f;
    }
}
__global__ void lgcn_dot_fb(const float* __restrict__ acc,
                            const int* __restrict__ users,
                            const int* __restrict__ items,
                            float* __restrict__ out) {
    int t = blockIdx.x * blockDim.x + threadIdx.x;
    int b = t >> 6;
    int d = t & 63;
    if (b < BATCH) {
        int u  = users[b];
        int it = items[b];
        float p = acc[u * D + d] * acc[(N_USERS + it) * D + d];
        #pragma unroll
        for (int off = 32; off; off >>= 1) p += __shfl_down(p, off, 64);
        if (d == 0) out[b] = p * (1.0f / 16.0f);
    }
}

extern "C" void kernel_launch(void* const* d_in, const int* in_sizes, int n_in,
                              void* d_out, int out_size, void* d_ws, size_t ws_size,
                              hipStream_t stream) {
    const float* user_emb = (const float*)d_in[0];
    const float* item_emb = (const float*)d_in[1];
    const int*   edge_row = (const int*)d_in[2];
    const int*   edge_col = (const int*)d_in[3];
    const float* edge_val = (const float*)d_in[4];
    const int*   users    = (const int*)d_in[5];
    const int*   items    = (const int*)d_in[6];
    float*       out      = (float*)d_out;

    const int TPB = 256;
    int init_blocks = (NELEM + TPB - 1) / TPB;
    int spmm_blocks = (N_TOTAL * 64 + TPB - 1) / TPB;       // wave per row
    int samp_blocks = (2 * BATCH * 64 + TPB - 1) / TPB;     // wave per sampled row
    int dot_blocks  = (BATCH * 64 + TPB - 1) / TPB;

    // workspace layout (bf16 layer buffers; fixed-capacity padded pairs)
    unsigned short* A = (unsigned short*)d_ws;   // E0 bf16, NELEM
    unsigned short* B = A + NELEM;               // E1 bf16
    unsigned short* C = B + NELEM;               // E2 bf16
    float* e3 = (float*)(C + NELEM);             // 2*BATCH*D f32
    int2*  pairs   = (int2*)(e3 + 2 * BATCH * D);  // NBUK*CAP + 1 (overflow sink)
    int*   cursor  = (int*)(pairs + (size_t)NBUK * CAP + 1);  // NBUK
    int*   row_ptr = cursor + NBUK;              // NBUK*RPB
    int*   row_cnt = row_ptr + NBUK * RPB;       // NBUK*RPB
    size_t req = (size_t)((char*)(row_cnt + NBUK * RPB) - (char*)d_ws);

    if (ws_size < req && ws_size >= (size_t)3 * NELEM * 4) {
        // fallback: round-1 atomic path (needs only 3*NELEM floats)
        float* acc = (float*)d_ws;
        float* Af  = acc + NELEM;
        float* Bf  = Af + NELEM;
        long long st = (long long)NNZ * 64;
        int sb = (int)((st + TPB - 1) / TPB);
        lgcn_init_fb<<<init_blocks, TPB, 0, stream>>>(user_emb, item_emb, acc, Af, Bf);
        lgcn_spmm_fb<<<sb, TPB, 0, stream>>>(edge_row, edge_col, edge_val, Af, Bf);
        lgcn_accum_fb<<<init_blocks, TPB, 0, stream>>>(acc, Bf, Af);
        lgcn_spmm_fb<<<sb, TPB, 0, stream>>>(edge_row, edge_col, edge_val, Bf, Af);
        lgcn_accum_fb<<<init_blocks, TPB, 0, stream>>>(acc, Af, Bf);
        lgcn_spmm_fb<<<sb, TPB, 0, stream>>>(edge_row, edge_col, edge_val, Af, Bf);
        lgcn_accum_fb<<<init_blocks, TPB, 0, stream>>>(acc, Bf, nullptr);
        lgcn_dot_fb<<<dot_blocks, TPB, 0, stream>>>(acc, users, items, out);
        return;
    }

    // init E0 bf16 + zero bucket cursors
    lgcn_init<<<init_blocks, TPB, 0, stream>>>(user_emb, item_emb, A, cursor);

    // binning: permutation counting-sort scatter -> in-LDS exact sort (emits CSR)
    lgcn_bucket_scatter<<<EB, TPB, 0, stream>>>(edge_row, edge_col, edge_val,
                                                cursor, pairs);
    lgcn_bucket_sort<<<NBUK, TPB, 0, stream>>>(pairs, cursor, row_ptr, row_cnt);

    // layers 1,2 full width (bf16); layer 3 only at sampled rows (f32)
    lgcn_spmm_csr<<<spmm_blocks, TPB, 0, stream>>>(pairs, row_ptr, row_cnt, A, B);
    lgcn_spmm_csr<<<spmm_blocks, TPB, 0, stream>>>(pairs, row_ptr, row_cnt, B, C);
    lgcn_spmm_sampled<<<samp_blocks, TPB, 0, stream>>>(pairs, row_ptr, row_cnt, C,
                                                       users, items, e3);

    // gamma
    lgcn_dot<<<dot_blocks, TPB, 0, stream>>>(user_emb, item_emb, B, C, e3,
                                             users, items, out);
}

// Round 8
// 591.717 us; speedup vs baseline: 1.2805x; 1.2805x over previous
//
#include <hip/hip_runtime.h>
#include <hip/hip_bf16.h>

// LightGCN forward on MI355X — round 8.
// r5-r7 evidence: single-pass binning 8192-edge chunks -> 1172 buckets forces 56B
//   runs; every variant loses (write-amp 181MB / LDS 111KB occ 9.6% / L2 thrash
//   526MB fetch). r8: two-level radix, direct scatter both passes (runs 221/256
//   edges -> L2 merges, no LDS staging), in-place per-bucket row sort (51KB LDS,
//   3 blk/CU). A/B bf16 alias the dead pass-1 region; ws ~136.6MB.

#define N_USERS  100000
#define N_ITEMS  50000
#define N_TOTAL  150000          // N_USERS + N_ITEMS
#define D        64
#define NNZ      6400000
#define BATCH    4096
#define NELEM    (N_TOTAL * D)   // 9,600,000
#define CHUNK    8192
#define EB       ((NNZ + CHUNK - 1) / CHUNK)  // 782

#define NC       37              // coarse buckets (4096 rows each)
#define CROWS    4096
#define CAPC     180224          // coarse capacity = mean 174763 + 13 sigma (22*CHUNK)
#define NCH2     (CAPC / CHUNK)  // 22 chunks per coarse region
#define NF       32              // fine buckets per coarse (128 rows each)
#define RPB      128
#define NBUK     (NC * NF)       // 1184 fine buckets
#define CAPF     6400            // fine capacity = mean 5461 + 12.7 sigma

__device__ __forceinline__ float bf2f(unsigned short h) {
    return __uint_as_float(((unsigned int)h) << 16);
}

// ---------- zero cursors ----------
__global__ void lgcn_zero(int* __restrict__ cur1, int* __restrict__ cur2) {
    int i = threadIdx.x;
    if (i < NC) cur1[i] = 0;
    for (int j = i; j < NBUK; j += 256) cur2[j] = 0;
}

// ---------- pass 1: COO -> 37 coarse buckets, direct scatter ----------
// X pair: x = (row_in_coarse<<18) | col  (12b + 18b), y = val bits
__global__ void __launch_bounds__(256)
lgcn_scatter1(const int*   __restrict__ rows,
              const int*   __restrict__ cols,
              const float* __restrict__ vals,
              int*         __restrict__ cur1,
              int2*        __restrict__ X) {
    __shared__ int h[NC];
    __shared__ int gb[NC];
    int tid = threadIdx.x;
    int s = blockIdx.x * CHUNK;
    int e_end = s + CHUNK; if (e_end > NNZ) e_end = NNZ;

    if (tid < NC) h[tid] = 0;
    __syncthreads();
    for (int e = s + tid; e < e_end; e += 256)
        atomicAdd(&h[rows[e] >> 12], 1);
    __syncthreads();
    if (tid < NC) {
        int c = h[tid];
        gb[tid] = c ? atomicAdd(&cur1[tid], c) : 0;
        h[tid] = 0;
    }
    __syncthreads();
    for (int e = s + tid; e < e_end; e += 256) {
        int r = rows[e];
        int c = r >> 12;
        int rank = atomicAdd(&h[c], 1);
        int o = gb[c] + rank;
        int2 p;
        p.x = ((r & 4095) << 18) | cols[e];
        p.y = __float_as_int(vals[e]);
        X[(o < CAPC) ? ((size_t)c * CAPC + o) : ((size_t)NC * CAPC)] = p;
    }
}

// ---------- pass 2: coarse region -> 32 fine buckets, direct scatter ----------
// Y pair: x = (row_in_fine<<18) | col  (7b + 18b), y = val bits
__global__ void __launch_bounds__(256)
lgcn_scatter2(const int2* __restrict__ X,
              const int*  __restrict__ cur1,
              int*        __restrict__ cur2,
              int2*       __restrict__ Y) {
    int c = blockIdx.x / NCH2;
    int ch = blockIdx.x % NCH2;
    int cnt_c = cur1[c]; if (cnt_c > CAPC) cnt_c = CAPC;
    int s = ch * CHUNK;
    int n = cnt_c - s; if (n > CHUNK) n = CHUNK;
    if (n <= 0) return;                       // uniform per block

    __shared__ int h[NF];
    __shared__ int gb[NF];
    int tid = threadIdx.x;
    size_t base = (size_t)c * CAPC + s;

    if (tid < NF) h[tid] = 0;
    __syncthreads();
    for (int i = tid; i < n; i += 256)
        atomicAdd(&h[X[base + i].x >> 25], 1);   // (lr12>>7) = fine bucket
    __syncthreads();
    if (tid < NF) {
        int cc = h[tid];
        gb[tid] = cc ? atomicAdd(&cur2[c * NF + tid], cc) : 0;
        h[tid] = 0;
    }
    __syncthreads();
    for (int i = tid; i < n; i += 256) {
        int2 p = X[base + i];
        int lr12 = p.x >> 18;
        int f = lr12 >> 7;
        int rank = atomicAdd(&h[f], 1);
        int o = gb[f] + rank;
        int2 q;
        q.x = ((lr12 & 127) << 18) | (p.x & 0x3FFFF);
        q.y = p.y;
        Y[(o < CAPF) ? ((size_t)(c * NF + f) * CAPF + o) : ((size_t)NBUK * CAPF)] = q;
    }
}

// ---------- pass 3: in-place per-fine-bucket row-exact sort; emit CSR ----------
__global__ void __launch_bounds__(256)
lgcn_bucket_sort(int2* __restrict__ Y,
                 const int* __restrict__ cur2,
                 int* __restrict__ row_ptr,
                 int* __restrict__ row_cnt) {
    __shared__ int2 buf[CAPF];         // 51.2 KB -> 3 blocks/CU
    __shared__ int  h[RPB];
    __shared__ int  base[RPB];
    int tid = threadIdx.x;
    int fb = blockIdx.x;
    size_t start = (size_t)fb * CAPF;
    int cnt = cur2[fb]; if (cnt > CAPF) cnt = CAPF;

    for (int i = tid; i < cnt; i += 256) buf[i] = Y[start + i];
    if (tid < RPB) h[tid] = 0;
    __syncthreads();
    for (int i = tid; i < cnt; i += 256) atomicAdd(&h[buf[i].x >> 18], 1);
    __syncthreads();

    // exclusive scan of h[0..127]
    int v = (tid < RPB) ? h[tid] : 0;
    int sum = v;
    #pragma unroll
    for (int off = 1; off < RPB; off <<= 1) {
        if (tid < RPB) base[tid] = sum;
        __syncthreads();
        if (tid >= off && tid < RPB) sum += base[tid - off];
        __syncthreads();
    }
    if (tid < RPB) {
        int excl = sum - v;
        base[tid] = excl;
        int gr = (fb >> 5) * CROWS + (fb & 31) * RPB + tid;
        if (gr < N_TOTAL) {
            row_ptr[gr] = (int)start + excl;
            row_cnt[gr] = v;
        }
        h[tid] = 0;                    // reuse as per-row cursor
    }
    __syncthreads();

    for (int i = tid; i < cnt; i += 256) {
        int2 p = buf[i];
        int lr = p.x >> 18;
        int rank = atomicAdd(&h[lr], 1);
        Y[start + base[lr] + rank] = p;   // in place; window 51KB -> L2
    }
}

// ---------- init A = bf16(concat(user,item)) (after pass 2: A aliases X) ------
__global__ void lgcn_init_A(const float* __restrict__ user_emb,
                            const float* __restrict__ item_emb,
                            unsigned short* __restrict__ A) {
    int i = blockIdx.x * blockDim.x + threadIdx.x;
    if (i < NELEM) {
        float v = (i < N_USERS * D) ? user_emb[i] : item_emb[i - N_USERS * D];
        __hip_bfloat16 b = __float2bfloat16(v);   // RNE
        A[i] = *(unsigned short*)&b;
    }
}

// ---------- SpMM: wave per row, bf16 gathers, bf16 output ----------
__global__ void lgcn_spmm_csr(const int2* __restrict__ pairs,
                              const int*  __restrict__ row_ptr,
                              const int*  __restrict__ row_cnt,
                              const unsigned short* __restrict__ cur,
                              unsigned short* __restrict__ nxt) {
    int t = blockIdx.x * blockDim.x + threadIdx.x;
    int r = t >> 6;
    int lane = t & 63;
    if (r >= N_TOTAL) return;
    int start = row_ptr[r];
    int cnt   = row_cnt[r];
    float sum0 = 0.f, sum1 = 0.f;
    for (int base = 0; base < cnt; base += 64) {
        int idx = base + lane;
        int2 p = {0, 0};
        if (idx < cnt) p = pairs[start + idx];     // coalesced dwordx2
        int m = cnt - base; if (m > 64) m = 64;
        int j = 0;
        for (; j + 8 <= m; j += 8) {               // 8 outstanding gathers
            float acc[8];
            #pragma unroll
            for (int k = 0; k < 8; k++) {
                int   c = __shfl(p.x, j + k, 64);
                float v = __int_as_float(__shfl(p.y, j + k, 64));
                acc[k] = v * bf2f(cur[(c & 0x3FFFF) * D + lane]);
            }
            sum0 += acc[0] + acc[2] + acc[4] + acc[6];
            sum1 += acc[1] + acc[3] + acc[5] + acc[7];
        }
        for (; j < m; j++) {
            int   c = __shfl(p.x, j, 64);
            float v = __int_as_float(__shfl(p.y, j, 64));
            sum0 += v * bf2f(cur[(c & 0x3FFFF) * D + lane]);
        }
    }
    __hip_bfloat16 o = __float2bfloat16(sum0 + sum1);   // RNE
    nxt[r * D + lane] = *(unsigned short*)&o;
}

// ---------- layer 3 at sampled rows only: e3[s,:] = (A @ E2)[row(s),:] (f32) ----
__global__ void lgcn_spmm_sampled(const int2* __restrict__ pairs,
                                  const int*  __restrict__ row_ptr,
                                  const int*  __restrict__ row_cnt,
                                  const unsigned short* __restrict__ cur,
                                  const int* __restrict__ users,
                                  const int* __restrict__ items,
                                  float* __restrict__ e3) {
    int t = blockIdx.x * blockDim.x + threadIdx.x;
    int s = t >> 6;
    int lane = t & 63;
    if (s >= 2 * BATCH) return;
    int r = (s < BATCH) ? users[s] : (N_USERS + items[s - BATCH]);
    int start = row_ptr[r];
    int cnt   = row_cnt[r];
    float sum0 = 0.f, sum1 = 0.f;
    for (int base = 0; base < cnt; base += 64) {
        int idx = base + lane;
        int2 p = {0, 0};
        if (idx < cnt) p = pairs[start + idx];
        int m = cnt - base; if (m > 64) m = 64;
        int j = 0;
        for (; j + 8 <= m; j += 8) {
            float acc[8];
            #pragma unroll
            for (int k = 0; k < 8; k++) {
                int   c = __shfl(p.x, j + k, 64);
                float v = __int_as_float(__shfl(p.y, j + k, 64));
                acc[k] = v * bf2f(cur[(c & 0x3FFFF) * D + lane]);
            }
            sum0 += acc[0] + acc[2] + acc[4] + acc[6];
            sum1 += acc[1] + acc[3] + acc[5] + acc[7];
        }
        for (; j < m; j++) {
            int   c = __shfl(p.x, j, 64);
            float v = __int_as_float(__shfl(p.y, j, 64));
            sum0 += v * bf2f(cur[(c & 0x3FFFF) * D + lane]);
        }
    }
    e3[s * D + lane] = sum0 + sum1;
}

// ---------- dot: gamma = <E0+E1+E2+E3>_u . <E0+E1+E2+E3>_i / 16 ----------
__global__ void lgcn_dot(const float* __restrict__ user_emb,
                         const float* __restrict__ item_emb,
                         const unsigned short* __restrict__ E1,
                         const unsigned short* __restrict__ E2,
                         const float* __restrict__ e3,
                         const int* __restrict__ users,
                         const int* __restrict__ items,
                         float* __restrict__ out) {
    int t = blockIdx.x * blockDim.x + threadIdx.x;
    int b = t >> 6;
    int d = t & 63;
    if (b < BATCH) {
        int u  = users[b];
        int it = items[b];
        int ur = u * D + d;
        int ir = (N_USERS + it) * D + d;
        float au = user_emb[ur] + bf2f(E1[ur]) + bf2f(E2[ur]) + e3[b * D + d];
        float ai = item_emb[it * D + d] + bf2f(E1[ir]) + bf2f(E2[ir])
                 + e3[(BATCH + b) * D + d];
        float p = au * ai;
        #pragma unroll
        for (int off = 32; off; off >>= 1) p += __shfl_down(p, off, 64);
        if (d == 0) out[b] = p * (1.0f / 16.0f);
    }
}

// ---------- round-1 fallback (atomic scatter) if ws too small ----------
__global__ void lgcn_init_fb(const float* __restrict__ user_emb,
                             const float* __restrict__ item_emb,
                             float* __restrict__ acc,
                             float* __restrict__ cur,
                             float* __restrict__ nxt) {
    int i = blockIdx.x * blockDim.x + threadIdx.x;
    if (i < NELEM) {
        float v = (i < N_USERS * D) ? user_emb[i] : item_emb[i - N_USERS * D];
        acc[i] = v; cur[i] = v; nxt[i] = 0.0f;
    }
}
__global__ void lgcn_spmm_fb(const int* __restrict__ rows,
                             const int* __restrict__ cols,
                             const float* __restrict__ vals,
                             const float* __restrict__ cur,
                             float* __restrict__ nxt) {
    long long t = (long long)blockIdx.x * blockDim.x + threadIdx.x;
    int e = (int)(t >> 6);
    int d = (int)(t & 63);
    if (e < NNZ) {
        float x = cur[cols[e] * D + d];
        unsafeAtomicAdd(&nxt[rows[e] * D + d], vals[e] * x);
    }
}
__global__ void lgcn_accum_fb(float* __restrict__ acc,
                              const float* __restrict__ src,
                              float* __restrict__ to_zero) {
    int i = blockIdx.x * blockDim.x + threadIdx.x;
    if (i < NELEM) {
        acc[i] += src[i];
        if (to_zero) to_zero[i] = 0.0f;
    }
}
__global__ void lgcn_dot_fb(const float* __restrict__ acc,
                            const int* __restrict__ users,
                            const int* __restrict__ items,
                            float* __restrict__ out) {
    int t = blockIdx.x * blockDim.x + threadIdx.x;
    int b = t >> 6;
    int d = t & 63;
    if (b < BATCH) {
        int u  = users[b];
        int it = items[b];
        float p = acc[u * D + d] * acc[(N_USERS + it) * D + d];
        #pragma unroll
        for (int off = 32; off; off >>= 1) p += __shfl_down(p, off, 64);
        if (d == 0) out[b] = p * (1.0f / 16.0f);
    }
}

extern "C" void kernel_launch(void* const* d_in, const int* in_sizes, int n_in,
                              void* d_out, int out_size, void* d_ws, size_t ws_size,
                              hipStream_t stream) {
    const float* user_emb = (const float*)d_in[0];
    const float* item_emb = (const float*)d_in[1];
    const int*   edge_row = (const int*)d_in[2];
    const int*   edge_col = (const int*)d_in[3];
    const float* edge_val = (const float*)d_in[4];
    const int*   users    = (const int*)d_in[5];
    const int*   items    = (const int*)d_in[6];
    float*       out      = (float*)d_out;

    const int TPB = 256;
    int init_blocks = (NELEM + TPB - 1) / TPB;
    int spmm_blocks = (N_TOTAL * 64 + TPB - 1) / TPB;       // wave per row
    int samp_blocks = (2 * BATCH * 64 + TPB - 1) / TPB;     // wave per sampled row
    int dot_blocks  = (BATCH * 64 + TPB - 1) / TPB;

    // workspace layout:
    //   X (coarse pairs, +1 sink)  — dead after pass 2; A,B bf16 alias it
    //   Y (fine pairs, +1 sink)    — final row-sorted CSR pairs (in-place sort)
    //   C bf16, e3 f32, cursors, row_ptr/row_cnt
    int2* X = (int2*)d_ws;                              // NC*CAPC + 1
    int2* Y = X + (size_t)NC * CAPC + 1;                // NBUK*CAPF + 1
    unsigned short* C = (unsigned short*)(Y + (size_t)NBUK * CAPF + 1);  // NELEM
    float* e3 = (float*)(C + NELEM);                    // 2*BATCH*D
    int* cur1 = (int*)(e3 + 2 * BATCH * D);             // NC
    int* cur2 = cur1 + NC;                              // NBUK
    int* row_ptr = cur2 + NBUK;                         // NBUK*RPB
    int* row_cnt = row_ptr + NBUK * RPB;                // NBUK*RPB
    size_t req = (size_t)((char*)(row_cnt + NBUK * RPB) - (char*)d_ws);
    unsigned short* A = (unsigned short*)X;             // alias: init after pass 2
    unsigned short* B = A + NELEM;                      // alias: 38.4MB <= 53.3MB

    if (ws_size < req && ws_size >= (size_t)3 * NELEM * 4) {
        // fallback: round-1 atomic path (needs only 3*NELEM floats)
        float* acc = (float*)d_ws;
        float* Af  = acc + NELEM;
        float* Bf  = Af + NELEM;
        long long st = (long long)NNZ * 64;
        int sb = (int)((st + TPB - 1) / TPB);
        lgcn_init_fb<<<init_blocks, TPB, 0, stream>>>(user_emb, item_emb, acc, Af, Bf);
        lgcn_spmm_fb<<<sb, TPB, 0, stream>>>(edge_row, edge_col, edge_val, Af, Bf);
        lgcn_accum_fb<<<init_blocks, TPB, 0, stream>>>(acc, Bf, Af);
        lgcn_spmm_fb<<<sb, TPB, 0, stream>>>(edge_row, edge_col, edge_val, Bf, Af);
        lgcn_accum_fb<<<init_blocks, TPB, 0, stream>>>(acc, Af, Bf);
        lgcn_spmm_fb<<<sb, TPB, 0, stream>>>(edge_row, edge_col, edge_val, Af, Bf);
        lgcn_accum_fb<<<init_blocks, TPB, 0, stream>>>(acc, Bf, nullptr);
        lgcn_dot_fb<<<dot_blocks, TPB, 0, stream>>>(acc, users, items, out);
        return;
    }

    // two-level radix binning + in-place row sort
    lgcn_zero<<<1, TPB, 0, stream>>>(cur1, cur2);
    lgcn_scatter1<<<EB, TPB, 0, stream>>>(edge_row, edge_col, edge_val, cur1, X);
    lgcn_scatter2<<<NC * NCH2, TPB, 0, stream>>>(X, cur1, cur2, Y);
    lgcn_bucket_sort<<<NBUK, TPB, 0, stream>>>(Y, cur2, row_ptr, row_cnt);

    // E0 bf16 (A aliases dead X region)
    lgcn_init_A<<<init_blocks, TPB, 0, stream>>>(user_emb, item_emb, A);

    // layers 1,2 full width (bf16); layer 3 only at sampled rows (f32)
    lgcn_spmm_csr<<<spmm_blocks, TPB, 0, stream>>>(Y, row_ptr, row_cnt, A, B);
    lgcn_spmm_csr<<<spmm_blocks, TPB, 0, stream>>>(Y, row_ptr, row_cnt, B, C);
    lgcn_spmm_sampled<<<samp_blocks, TPB, 0, stream>>>(Y, row_ptr, row_cnt, C,
                                                       users, items, e3);

    // gamma
    lgcn_dot<<<dot_blocks, TPB, 0, stream>>>(user_emb, item_emb, B, C, e3,
                                             users, items, out);
}

// Round 9
// 524.939 us; speedup vs baseline: 1.4434x; 1.1272x over previous
//
#include <hip/hip_runtime.h>
#include <hip/hip_bf16.h>

// LightGCN forward on MI355X — round 9.
// r8 evidence: binning fixed (two-level radix); spmm_csr = 150us/layer with
//   VALUBusy 49.5%, occ 76%, FETCH 355MB @2.4TB/s -> ~half issue-bound.
// r9: dual-edge SpMM — wave splits into two 32-lane halves, each half handles a
//   different edge, each lane loads a dword (2 bf16 dims). Halves shfl/load/addr
//   per edge; cross-half combine via shfl_xor(32); packed uint stores.

#define N_USERS  100000
#define N_ITEMS  50000
#define N_TOTAL  150000          // N_USERS + N_ITEMS
#define D        64
#define NNZ      6400000
#define BATCH    4096
#define NELEM    (N_TOTAL * D)   // 9,600,000
#define CHUNK    8192
#define EB       ((NNZ + CHUNK - 1) / CHUNK)  // 782

#define NC       37              // coarse buckets (4096 rows each)
#define CROWS    4096
#define CAPC     180224          // coarse capacity = mean 174763 + 13 sigma
#define NCH2     (CAPC / CHUNK)  // 22 chunks per coarse region
#define NF       32              // fine buckets per coarse (128 rows each)
#define RPB      128
#define NBUK     (NC * NF)       // 1184 fine buckets
#define CAPF     6400            // fine capacity = mean 5461 + 12.7 sigma

__device__ __forceinline__ float bf2f(unsigned short h) {
    return __uint_as_float(((unsigned int)h) << 16);
}

// ---------- zero cursors ----------
__global__ void lgcn_zero(int* __restrict__ cur1, int* __restrict__ cur2) {
    int i = threadIdx.x;
    if (i < NC) cur1[i] = 0;
    for (int j = i; j < NBUK; j += 256) cur2[j] = 0;
}

// ---------- pass 1: COO -> 37 coarse buckets, direct scatter ----------
// X pair: x = (row_in_coarse<<18) | col  (12b + 18b), y = val bits
__global__ void __launch_bounds__(256)
lgcn_scatter1(const int*   __restrict__ rows,
              const int*   __restrict__ cols,
              const float* __restrict__ vals,
              int*         __restrict__ cur1,
              int2*        __restrict__ X) {
    __shared__ int h[NC];
    __shared__ int gb[NC];
    int tid = threadIdx.x;
    int s = blockIdx.x * CHUNK;
    int e_end = s + CHUNK; if (e_end > NNZ) e_end = NNZ;

    if (tid < NC) h[tid] = 0;
    __syncthreads();
    for (int e = s + tid; e < e_end; e += 256)
        atomicAdd(&h[rows[e] >> 12], 1);
    __syncthreads();
    if (tid < NC) {
        int c = h[tid];
        gb[tid] = c ? atomicAdd(&cur1[tid], c) : 0;
        h[tid] = 0;
    }
    __syncthreads();
    for (int e = s + tid; e < e_end; e += 256) {
        int r = rows[e];
        int c = r >> 12;
        int rank = atomicAdd(&h[c], 1);
        int o = gb[c] + rank;
        int2 p;
        p.x = ((r & 4095) << 18) | cols[e];
        p.y = __float_as_int(vals[e]);
        X[(o < CAPC) ? ((size_t)c * CAPC + o) : ((size_t)NC * CAPC)] = p;
    }
}

// ---------- pass 2: coarse region -> 32 fine buckets, direct scatter ----------
__global__ void __launch_bounds__(256)
lgcn_scatter2(const int2* __restrict__ X,
              const int*  __restrict__ cur1,
              int*        __restrict__ cur2,
              int2*       __restrict__ Y) {
    int c = blockIdx.x / NCH2;
    int ch = blockIdx.x % NCH2;
    int cnt_c = cur1[c]; if (cnt_c > CAPC) cnt_c = CAPC;
    int s = ch * CHUNK;
    int n = cnt_c - s; if (n > CHUNK) n = CHUNK;
    if (n <= 0) return;                       // uniform per block

    __shared__ int h[NF];
    __shared__ int gb[NF];
    int tid = threadIdx.x;
    size_t base = (size_t)c * CAPC + s;

    if (tid < NF) h[tid] = 0;
    __syncthreads();
    for (int i = tid; i < n; i += 256)
        atomicAdd(&h[X[base + i].x >> 25], 1);   // (lr12>>7) = fine bucket
    __syncthreads();
    if (tid < NF) {
        int cc = h[tid];
        gb[tid] = cc ? atomicAdd(&cur2[c * NF + tid], cc) : 0;
        h[tid] = 0;
    }
    __syncthreads();
    for (int i = tid; i < n; i += 256) {
        int2 p = X[base + i];
        int lr12 = p.x >> 18;
        int f = lr12 >> 7;
        int rank = atomicAdd(&h[f], 1);
        int o = gb[f] + rank;
        int2 q;
        q.x = ((lr12 & 127) << 18) | (p.x & 0x3FFFF);
        q.y = p.y;
        Y[(o < CAPF) ? ((size_t)(c * NF + f) * CAPF + o) : ((size_t)NBUK * CAPF)] = q;
    }
}

// ---------- pass 3: in-place per-fine-bucket row-exact sort; emit CSR ----------
__global__ void __launch_bounds__(256)
lgcn_bucket_sort(int2* __restrict__ Y,
                 const int* __restrict__ cur2,
                 int* __restrict__ row_ptr,
                 int* __restrict__ row_cnt) {
    __shared__ int2 buf[CAPF];         // 51.2 KB -> 3 blocks/CU
    __shared__ int  h[RPB];
    __shared__ int  base[RPB];
    int tid = threadIdx.x;
    int fb = blockIdx.x;
    size_t start = (size_t)fb * CAPF;
    int cnt = cur2[fb]; if (cnt > CAPF) cnt = CAPF;

    for (int i = tid; i < cnt; i += 256) buf[i] = Y[start + i];
    if (tid < RPB) h[tid] = 0;
    __syncthreads();
    for (int i = tid; i < cnt; i += 256) atomicAdd(&h[buf[i].x >> 18], 1);
    __syncthreads();

    // exclusive scan of h[0..127]
    int v = (tid < RPB) ? h[tid] : 0;
    int sum = v;
    #pragma unroll
    for (int off = 1; off < RPB; off <<= 1) {
        if (tid < RPB) base[tid] = sum;
        __syncthreads();
        if (tid >= off && tid < RPB) sum += base[tid - off];
        __syncthreads();
    }
    if (tid < RPB) {
        int excl = sum - v;
        base[tid] = excl;
        int gr = (fb >> 5) * CROWS + (fb & 31) * RPB + tid;
        if (gr < N_TOTAL) {
            row_ptr[gr] = (int)start + excl;
            row_cnt[gr] = v;
        }
        h[tid] = 0;                    // reuse as per-row cursor
    }
    __syncthreads();

    for (int i = tid; i < cnt; i += 256) {
        int2 p = buf[i];
        int lr = p.x >> 18;
        int rank = atomicAdd(&h[lr], 1);
        Y[start + base[lr] + rank] = p;   // in place; window 51KB -> L2
    }
}

// ---------- init A = bf16(concat(user,item)) (after pass 2: A aliases X) ------
__global__ void lgcn_init_A(const float* __restrict__ user_emb,
                            const float* __restrict__ item_emb,
                            unsigned short* __restrict__ A) {
    int i = blockIdx.x * blockDim.x + threadIdx.x;
    if (i < NELEM) {
        float v = (i < N_USERS * D) ? user_emb[i] : item_emb[i - N_USERS * D];
        __hip_bfloat16 b = __float2bfloat16(v);   // RNE
        A[i] = *(unsigned short*)&b;
    }
}

// ---------- SpMM: wave per row, dual-edge (2 edges per wave-iter) ----------
// lane = 32*half + hl; half h processes edge (jj+2k+h); lane loads a dword
// (dims 2hl, 2hl+1). Cross-half combine via shfl_xor(32); packed uint store.
__global__ void lgcn_spmm_csr(const int2* __restrict__ pairs,
                              const int*  __restrict__ row_ptr,
                              const int*  __restrict__ row_cnt,
                              const unsigned short* __restrict__ cur,
                              unsigned short* __restrict__ nxt) {
    const unsigned int* __restrict__ cur32 = (const unsigned int*)cur;
    int t = blockIdx.x * blockDim.x + threadIdx.x;
    int r = t >> 6;
    int lane = t & 63;
    if (r >= N_TOTAL) return;
    int halfid = lane >> 5;
    int hl = lane & 31;
    int start = row_ptr[r];
    int cnt   = row_cnt[r];
    float sA = 0.f, sB = 0.f;
    for (int base = 0; base < cnt; base += 64) {
        int idx = base + lane;
        int2 p = {0, 0};
        if (idx < cnt) p = pairs[start + idx];     // coalesced dwordx2
        int m = cnt - base; if (m > 64) m = 64;
        int jj = 0;
        for (; jj + 8 <= m; jj += 8) {             // 8 edges, unguarded
            #pragma unroll
            for (int k = 0; k < 4; k++) {
                int sel = jj + 2 * k + halfid;
                int   c = __shfl(p.x, sel, 64);
                float v = __int_as_float(__shfl(p.y, sel, 64));
                unsigned int u = cur32[(c & 0x3FFFF) * 32 + hl];
                sA = fmaf(v, __uint_as_float(u << 16), sA);
                sB = fmaf(v, __uint_as_float(u & 0xFFFF0000u), sB);
            }
        }
        if (jj < m) {                              // tail: guarded (p=0 beyond cnt)
            #pragma unroll
            for (int k = 0; k < 4; k++) {
                int sel = jj + 2 * k + halfid;
                int   c = __shfl(p.x, sel, 64);
                float v = __int_as_float(__shfl(p.y, sel, 64));
                if (sel >= m) v = 0.f;
                unsigned int u = cur32[(c & 0x3FFFF) * 32 + hl];
                sA = fmaf(v, __uint_as_float(u << 16), sA);
                sB = fmaf(v, __uint_as_float(u & 0xFFFF0000u), sB);
            }
        }
    }
    sA += __shfl_xor(sA, 32, 64);
    sB += __shfl_xor(sB, 32, 64);
    if (halfid == 0) {
        __hip_bfloat16 a = __float2bfloat16(sA);   // RNE
        __hip_bfloat16 b = __float2bfloat16(sB);
        unsigned int lo = *(unsigned short*)&a;
        unsigned int hi = *(unsigned short*)&b;
        ((unsigned int*)nxt)[r * 32 + hl] = lo | (hi << 16);  // half-wave 128B
    }
}

// ---------- layer 3 at sampled rows only: e3[s,:] = (A @ E2)[row(s),:] (f32) ----
__global__ void lgcn_spmm_sampled(const int2* __restrict__ pairs,
                                  const int*  __restrict__ row_ptr,
                                  const int*  __restrict__ row_cnt,
                                  const unsigned short* __restrict__ cur,
                                  const int* __restrict__ users,
                                  const int* __restrict__ items,
                                  float* __restrict__ e3) {
    int t = blockIdx.x * blockDim.x + threadIdx.x;
    int s = t >> 6;
    int lane = t & 63;
    if (s >= 2 * BATCH) return;
    int r = (s < BATCH) ? users[s] : (N_USERS + items[s - BATCH]);
    int start = row_ptr[r];
    int cnt   = row_cnt[r];
    float sum0 = 0.f, sum1 = 0.f;
    for (int base = 0; base < cnt; base += 64) {
        int idx = base + lane;
        int2 p = {0, 0};
        if (idx < cnt) p = pairs[start + idx];
        int m = cnt - base; if (m > 64) m = 64;
        int j = 0;
        for (; j + 8 <= m; j += 8) {
            float acc[8];
            #pragma unroll
            for (int k = 0; k < 8; k++) {
                int   c = __shfl(p.x, j + k, 64);
                float v = __int_as_float(__shfl(p.y, j + k, 64));
                acc[k] = v * bf2f(cur[(c & 0x3FFFF) * D + lane]);
            }
            sum0 += acc[0] + acc[2] + acc[4] + acc[6];
            sum1 += acc[1] + acc[3] + acc[5] + acc[7];
        }
        for (; j < m; j++) {
            int   c = __shfl(p.x, j, 64);
            float v = __int_as_float(__shfl(p.y, j, 64));
            sum0 += v * bf2f(cur[(c & 0x3FFFF) * D + lane]);
        }
    }
    e3[s * D + lane] = sum0 + sum1;
}

// ---------- dot: gamma = <E0+E1+E2+E3>_u . <E0+E1+E2+E3>_i / 16 ----------
__global__ void lgcn_dot(const float* __restrict__ user_emb,
                         const float* __restrict__ item_emb,
                         const unsigned short* __restrict__ E1,
                         const unsigned short* __restrict__ E2,
                         const float* __restrict__ e3,
                         const int* __restrict__ users,
                         const int* __restrict__ items,
                         float* __restrict__ out) {
    int t = blockIdx.x * blockDim.x + threadIdx.x;
    int b = t >> 6;
    int d = t & 63;
    if (b < BATCH) {
        int u  = users[b];
        int it = items[b];
        int ur = u * D + d;
        int ir = (N_USERS + it) * D + d;
        float au = user_emb[ur] + bf2f(E1[ur]) + bf2f(E2[ur]) + e3[b * D + d];
        float ai = item_emb[it * D + d] + bf2f(E1[ir]) + bf2f(E2[ir])
                 + e3[(BATCH + b) * D + d];
        float p = au * ai;
        #pragma unroll
        for (int off = 32; off; off >>= 1) p += __shfl_down(p, off, 64);
        if (d == 0) out[b] = p * (1.0f / 16.0f);
    }
}

// ---------- round-1 fallback (atomic scatter) if ws too small ----------
__global__ void lgcn_init_fb(const float* __restrict__ user_emb,
                             const float* __restrict__ item_emb,
                             float* __restrict__ acc,
                             float* __restrict__ cur,
                             float* __restrict__ nxt) {
    int i = blockIdx.x * blockDim.x + threadIdx.x;
    if (i < NELEM) {
        float v = (i < N_USERS * D) ? user_emb[i] : item_emb[i - N_USERS * D];
        acc[i] = v; cur[i] = v; nxt[i] = 0.0f;
    }
}
__global__ void lgcn_spmm_fb(const int* __restrict__ rows,
                             const int* __restrict__ cols,
                             const float* __restrict__ vals,
                             const float* __restrict__ cur,
                             float* __restrict__ nxt) {
    long long t = (long long)blockIdx.x * blockDim.x + threadIdx.x;
    int e = (int)(t >> 6);
    int d = (int)(t & 63);
    if (e < NNZ) {
        float x = cur[cols[e] * D + d];
        unsafeAtomicAdd(&nxt[rows[e] * D + d], vals[e] * x);
    }
}
__global__ void lgcn_accum_fb(float* __restrict__ acc,
                              const float* __restrict__ src,
                              float* __restrict__ to_zero) {
    int i = blockIdx.x * blockDim.x + threadIdx.x;
    if (i < NELEM) {
        acc[i] += src[i];
        if (to_zero) to_zero[i] = 0.0f;
    }
}
__global__ void lgcn_dot_fb(const float* __restrict__ acc,
                            const int* __restrict__ users,
                            const int* __restrict__ items,
                            float* __restrict__ out) {
    int t = blockIdx.x * blockDim.x + threadIdx.x;
    int b = t >> 6;
    int d = t & 63;
    if (b < BATCH) {
        int u  = users[b];
        int it = items[b];
        float p = acc[u * D + d] * acc[(N_USERS + it) * D + d];
        #pragma unroll
        for (int off = 32; off; off >>= 1) p += __shfl_down(p, off, 64);
        if (d == 0) out[b] = p * (1.0f / 16.0f);
    }
}

extern "C" void kernel_launch(void* const* d_in, const int* in_sizes, int n_in,
                              void* d_out, int out_size, void* d_ws, size_t ws_size,
                              hipStream_t stream) {
    const float* user_emb = (const float*)d_in[0];
    const float* item_emb = (const float*)d_in[1];
    const int*   edge_row = (const int*)d_in[2];
    const int*   edge_col = (const int*)d_in[3];
    const float* edge_val = (const float*)d_in[4];
    const int*   users    = (const int*)d_in[5];
    const int*   items    = (const int*)d_in[6];
    float*       out      = (float*)d_out;

    const int TPB = 256;
    int init_blocks = (NELEM + TPB - 1) / TPB;
    int spmm_blocks = (N_TOTAL * 64 + TPB - 1) / TPB;       // wave per row
    int samp_blocks = (2 * BATCH * 64 + TPB - 1) / TPB;     // wave per sampled row
    int dot_blocks  = (BATCH * 64 + TPB - 1) / TPB;

    // workspace layout:
    //   X (coarse pairs, +1 sink)  — dead after pass 2; A,B bf16 alias it
    //   Y (fine pairs, +1 sink)    — final row-sorted CSR pairs (in-place sort)
    //   C bf16, e3 f32, cursors, row_ptr/row_cnt
    int2* X = (int2*)d_ws;                              // NC*CAPC + 1
    int2* Y = X + (size_t)NC * CAPC + 1;                // NBUK*CAPF + 1
    unsigned short* C = (unsigned short*)(Y + (size_t)NBUK * CAPF + 1);  // NELEM
    float* e3 = (float*)(C + NELEM);                    // 2*BATCH*D
    int* cur1 = (int*)(e3 + 2 * BATCH * D);             // NC
    int* cur2 = cur1 + NC;                              // NBUK
    int* row_ptr = cur2 + NBUK;                         // NBUK*RPB
    int* row_cnt = row_ptr + NBUK * RPB;                // NBUK*RPB
    size_t req = (size_t)((char*)(row_cnt + NBUK * RPB) - (char*)d_ws);
    unsigned short* A = (unsigned short*)X;             // alias: init after pass 2
    unsigned short* B = A + NELEM;                      // alias: 38.4MB <= 53.3MB

    if (ws_size < req && ws_size >= (size_t)3 * NELEM * 4) {
        // fallback: round-1 atomic path (needs only 3*NELEM floats)
        float* acc = (float*)d_ws;
        float* Af  = acc + NELEM;
        float* Bf  = Af + NELEM;
        long long st = (long long)NNZ * 64;
        int sb = (int)((st + TPB - 1) / TPB);
        lgcn_init_fb<<<init_blocks, TPB, 0, stream>>>(user_emb, item_emb, acc, Af, Bf);
        lgcn_spmm_fb<<<sb, TPB, 0, stream>>>(edge_row, edge_col, edge_val, Af, Bf);
        lgcn_accum_fb<<<init_blocks, TPB, 0, stream>>>(acc, Bf, Af);
        lgcn_spmm_fb<<<sb, TPB, 0, stream>>>(edge_row, edge_col, edge_val, Bf, Af);
        lgcn_accum_fb<<<init_blocks, TPB, 0, stream>>>(acc, Af, Bf);
        lgcn_spmm_fb<<<sb, TPB, 0, stream>>>(edge_row, edge_col, edge_val, Af, Bf);
        lgcn_accum_fb<<<init_blocks, TPB, 0, stream>>>(acc, Bf, nullptr);
        lgcn_dot_fb<<<dot_blocks, TPB, 0, stream>>>(acc, users, items, out);
        return;
    }

    // two-level radix binning + in-place row sort
    lgcn_zero<<<1, TPB, 0, stream>>>(cur1, cur2);
    lgcn_scatter1<<<EB, TPB, 0, stream>>>(edge_row, edge_col, edge_val, cur1, X);
    lgcn_scatter2<<<NC * NCH2, TPB, 0, stream>>>(X, cur1, cur2, Y);
    lgcn_bucket_sort<<<NBUK, TPB, 0, stream>>>(Y, cur2, row_ptr, row_cnt);

    // E0 bf16 (A aliases dead X region)
    lgcn_init_A<<<init_blocks, TPB, 0, stream>>>(user_emb, item_emb, A);

    // layers 1,2 full width (bf16); layer 3 only at sampled rows (f32)
    lgcn_spmm_csr<<<spmm_blocks, TPB, 0, stream>>>(Y, row_ptr, row_cnt, A, B);
    lgcn_spmm_csr<<<spmm_blocks, TPB, 0, stream>>>(Y, row_ptr, row_cnt, B, C);
    lgcn_spmm_sampled<<<samp_blocks, TPB, 0, stream>>>(Y, row_ptr, row_cnt, C,
                                                       users, items, e3);

    // gamma
    lgcn_dot<<<dot_blocks, TPB, 0, stream>>>(user_emb, item_emb, B, C, e3,
                                             users, items, out);
}